// Round 5
// baseline (64.183 us; speedup 1.0000x reference)
//
#include <hip/hip_runtime.h>

#define HWN 9216   // 96*96
#define SCALE 0.1767766952966369f

static __device__ __forceinline__ float rcp_fast(float x) {
  return __builtin_amdgcn_rcpf(x);
}
static __device__ __forceinline__ float rl_f(float x, int l) {
  return __int_as_float(__builtin_amdgcn_readlane(__float_as_int(x), l));
}
template <int C>
static __device__ __forceinline__ float dpps(float x) {  // sum step (0-fill)
  return x + __int_as_float(__builtin_amdgcn_update_dpp(
                 0, __float_as_int(x), C, 0xf, 0xf, true));
}
static __device__ __forceinline__ float wave_sum63(float x) {
  x = dpps<0x111>(x); x = dpps<0x112>(x); x = dpps<0x114>(x);
  x = dpps<0x118>(x); x = dpps<0x142>(x); x = dpps<0x143>(x);
  return x;  // lane 63 holds the 64-lane total
}

// ---------------- Kernel 0: weight prep ----------------
// w_qs = w_qk[:, :64] * SCALE
// w_vp0 = w_v[:, 0:32]  @ w_proj[0:32, :]   (head-0 half projection)
// w_vp1 = w_v[:, 32:64] @ w_proj[32:64, :]  (head-1 half projection)
extern "C" __global__ void __launch_bounds__(256) prep_kernel(
    const float* __restrict__ w_qk, const float* __restrict__ w_v,
    const float* __restrict__ w_proj, float* __restrict__ w_qs,
    float* __restrict__ w_vp0, float* __restrict__ w_vp1) {
  __shared__ float wvL[64 * 64];
  __shared__ float wpL[64 * 64];
  const int t = threadIdx.x;
#pragma unroll
  for (int rep = 0; rep < 16; ++rep) {
    const int idx = rep * 256 + t;
    wvL[idx] = w_v[idx];
    wpL[idx] = w_proj[idx];
    w_qs[idx] = w_qk[(idx >> 6) * 128 + (idx & 63)] * SCALE;
  }
  __syncthreads();
  const int r = t >> 2, c0 = (t & 3) * 16;
  float a0[16], a1[16];
#pragma unroll
  for (int cc = 0; cc < 16; ++cc) { a0[cc] = 0.f; a1[cc] = 0.f; }
  for (int d = 0; d < 32; ++d) {
    const float wv = wvL[r * 64 + d];
#pragma unroll
    for (int cc = 0; cc < 16; ++cc) a0[cc] += wv * wpL[d * 64 + c0 + cc];
  }
  for (int d = 32; d < 64; ++d) {
    const float wv = wvL[r * 64 + d];
#pragma unroll
    for (int cc = 0; cc < 16; ++cc) a1[cc] += wv * wpL[d * 64 + c0 + cc];
  }
#pragma unroll
  for (int cc = 0; cc < 16; ++cc) {
    w_vp0[r * 64 + c0 + cc] = a0[cc];
    w_vp1[r * 64 + c0 + cc] = a1[cc];
  }
}

// ---------------- Kernel 1: QKV' projection ----------------
// Grid 1152 = 288 px-blocks x 4 col-blocks. qkv row = 256 floats/pixel:
// [ q'*SCALE (64) | k (64) | v0' (64) | v1' (64) ]
extern "C" __global__ void __launch_bounds__(256) qkv_proj_kernel(
    const float* __restrict__ x, const float* __restrict__ w_qk,
    const float* __restrict__ w_qs, const float* __restrict__ w_vp0,
    const float* __restrict__ w_vp1, float* __restrict__ qkv) {
  __shared__ __align__(16) float A[64 * 64];   // [d][px]
  __shared__ __align__(16) float Wl[64 * 64];  // [d][c]
  const int t = threadIdx.x;
  const int bid = blockIdx.x;
  const int cb = bid & 3;
  const int pxblk = bid >> 2;
  const int b = (pxblk >= 144) ? 1 : 0;
  const int p0 = (pxblk - b * 144) * 64;
  const float* xb = x + b * (64 * HWN) + p0;
#pragma unroll
  for (int rep = 0; rep < 16; ++rep) {
    const int idx = rep * 256 + t;
    A[idx] = xb[(idx >> 6) * HWN + (idx & 63)];
  }
  const float* wsrc = (cb == 0) ? w_qs
                      : (cb == 1) ? (w_qk + 64)
                      : (cb == 2) ? w_vp0 : w_vp1;
  const int wld = (cb == 1) ? 128 : 64;
#pragma unroll
  for (int rep = 0; rep < 16; ++rep) {
    const int idx = rep * 256 + t;
    Wl[idx] = wsrc[(idx >> 6) * wld + (idx & 63)];
  }
  __syncthreads();
  const int pxg = t >> 4, cg = t & 15;
  float acc[4][4];
#pragma unroll
  for (int p = 0; p < 4; ++p)
#pragma unroll
    for (int c = 0; c < 4; ++c) acc[p][c] = 0.f;
#pragma unroll 4
  for (int d = 0; d < 64; ++d) {
    const float4 av = *(const float4*)&A[d * 64 + pxg * 4];
    const float4 wv4 = *(const float4*)&Wl[d * 64 + cg * 4];
    const float aa[4] = {av.x, av.y, av.z, av.w};
    const float ww[4] = {wv4.x, wv4.y, wv4.z, wv4.w};
#pragma unroll
    for (int p = 0; p < 4; ++p)
#pragma unroll
      for (int c = 0; c < 4; ++c) acc[p][c] += aa[p] * ww[c];
  }
  const int pixbase = b * HWN + p0 + pxg * 4;
#pragma unroll
  for (int p = 0; p < 4; ++p) {
    *(float4*)&qkv[(pixbase + p) * 256 + cb * 64 + cg * 4] =
        make_float4(acc[p][0], acc[p][1], acc[p][2], acc[p][3]);
  }
}

// ---------------- Kernel 2: fused attention ----------------
// WG = 512 thr = 8 waves; 2x4 pixel tile. Wave = pixel; lane = neighbor
// (QK/softmax) then lane = out-channel (PV). v pre-projected per head half.
extern "C" __global__ void __launch_bounds__(512, 4) attn_fused_kernel(
    const float* __restrict__ qkv, const float* __restrict__ sims,
    const float* __restrict__ b_proj, float* __restrict__ out) {
  __shared__ __align__(16) float kT[64 * 81];    // k transposed [d][cell]
  __shared__ __align__(16) float vL[80 * 128];   // [cell][v0'(64)|v1'(64)]
  __shared__ __align__(16) float simsL[80 * 9];  // 9 probs (+eps) per cell
  __shared__ __align__(16) float qL[8 * 64];     // q' per pixel
  __shared__ __align__(16) float wLds[8][104];   // [n*2+h] combine weights

  const int t = threadIdx.x;
  const int lane = t & 63;
  const int wvv = t >> 6;

  int wg = blockIdx.x;  // 2304 = 2 * 48 * 24
  const int bb = (wg >= 1152) ? 1 : 0;
  wg -= bb * 1152;
  const int i0 = (wg / 24) * 2;
  const int j0 = (wg % 24) * 4;
  const int rstart0 = max(min(i0 - 3, 88), 0);  // 8 staged rows
  const int cstart0 = max(min(j0 - 3, 86), 0);  // 10 staged cols

  const float* qkvb = qkv + bb * (HWN * 256);
  const float bp = b_proj[lane];

  // ---- stage k (transposed) + v' halo: wave wvv stages halo row wvv ----
  {
    const float* src =
        qkvb + ((rstart0 + wvv) * 96 + cstart0) * 256 + 64 + lane;
#pragma unroll
    for (int kk = 0; kk < 10; ++kk) {
      const int cell = wvv * 10 + kk;
      kT[lane * 81 + cell] = src[kk * 256];
      vL[cell * 128 + lane] = src[kk * 256 + 64];
      vL[cell * 128 + 64 + lane] = src[kk * 256 + 128];
    }
  }
  // ---- stage q' (pre-scaled) ----
  {
    const int qi = i0 + (wvv >> 2), qj = j0 + (wvv & 3);
    qL[wvv * 64 + lane] = qkvb[(qi * 96 + qj) * 256 + lane];
  }
  // ---- stage sims (+eps) ----
  {
    const int si = i0 >> 3, sj = j0 >> 3;
    int sp9[9];
#pragma unroll
    for (int s = 0; s < 9; ++s) {
      const int sr = min(max(si + s / 3 - 1, 0), 11);
      const int sc = min(max(sj + s % 3 - 1, 0), 11);
      sp9[s] = sr * 12 + sc;
    }
    const float* simsb = sims + bb * (HWN * 144);
    for (int el = t; el < 720; el += 512) {
      const int cell = el / 9, s = el - (el / 9) * 9;
      const int r = cell / 10, c = cell - (cell / 10) * 10;
      simsL[cell * 9 + s] =
          simsb[((rstart0 + r) * 96 + (cstart0 + c)) * 144 + sp9[s]] + 1e-12f;
    }
  }
  __syncthreads();

  // ---- per-wave: pixel (i,j); lane owns neighbor nn ----
  const int i = i0 + (wvv >> 2), j = j0 + (wvv & 3);
  const int dr = max(min(i - 3, 89), 0) - rstart0;  // 0..1
  const int dc = max(min(j - 3, 89), 0) - cstart0;  // 0..3
  const int nn = min(lane, 48);
  const int cell = (dr + nn / 7) * 10 + (dc + nn % 7);

  // QK: k via per-lane b32 (imm offsets), q via uniform b128 reads
  const float* qp = &qL[wvv * 64];
  const float* kp = &kT[cell];
  float a0 = 0.f, a1 = 0.f;
#pragma unroll
  for (int g = 0; g < 8; ++g) {
    const float4 q4 = *(const float4*)(qp + g * 4);
    a0 += q4.x * kp[(g * 4 + 0) * 81] + q4.y * kp[(g * 4 + 1) * 81] +
          q4.z * kp[(g * 4 + 2) * 81] + q4.w * kp[(g * 4 + 3) * 81];
  }
#pragma unroll
  for (int g = 8; g < 16; ++g) {
    const float4 q4 = *(const float4*)(qp + g * 4);
    a1 += q4.x * kp[(g * 4 + 0) * 81] + q4.y * kp[(g * 4 + 1) * 81] +
          q4.z * kp[(g * 4 + 2) * 81] + q4.w * kp[(g * 4 + 3) * 81];
  }
  // softmax without max-subtraction (logits are O(+-6); f32 has headroom)
  const float e0 = (lane < 49) ? __expf(a0) : 0.f;
  const float e1 = (lane < 49) ? __expf(a1) : 0.f;

  // Z_s = sum_n (Pj+eps)*e per head; combine weights
  const float* spL = &simsL[cell * 9];
  float tv[9];
#pragma unroll
  for (int s = 0; s < 9; ++s) tv[s] = spL[s];
  const float* cpc = &simsL[((i - rstart0) * 10 + (j - cstart0)) * 9];
  float w0 = 0.f, w1 = 0.f;
#pragma unroll
  for (int s = 0; s < 9; ++s) {
    const float Z0 = rl_f(wave_sum63(tv[s] * e0), 63);
    const float Z1 = rl_f(wave_sum63(tv[s] * e1), 63);
    const float pis = cpc[s];
    w0 += tv[s] * (pis * rcp_fast(Z0));
    w1 += tv[s] * (pis * rcp_fast(Z1));
  }
  w0 *= e0;  // wcomb[h0][n=lane]
  w1 *= e1;  // wcomb[h1][n=lane]
  if (lane < 49) {
    *(float2*)&wLds[wvv][lane * 2] = make_float2(w0, w1);
  }

  // PV: lane = out channel; weights via uniform b128 broadcast;
  // v' halves via conflict-free b32 with immediate cell offsets.
  const float* vbl = &vL[(dr * 10 + dc) * 128 + lane];
  const float* wrow = &wLds[wvv][0];
  float o0 = bp, o1 = 0.f, o2 = 0.f, o3 = 0.f;
#pragma unroll
  for (int m = 0; m < 24; ++m) {
    const float4 w4 = *(const float4*)(wrow + m * 4);
    const int na = 2 * m, nb = 2 * m + 1;
    const int offa = ((na / 7) * 10 + na % 7) * 128;
    const int offb = ((nb / 7) * 10 + nb % 7) * 128;
    o0 += w4.x * vbl[offa];
    o1 += w4.y * vbl[offa + 64];
    o2 += w4.z * vbl[offb];
    o3 += w4.w * vbl[offb + 64];
  }
  {
    const float2 wl = *(const float2*)(wrow + 96);  // n = 48
    o0 += wl.x * vbl[66 * 128];
    o1 += wl.y * vbl[66 * 128 + 64];
  }
  out[(bb * 64 + lane) * HWN + i * 96 + j] = (o0 + o1) + (o2 + o3);
}

extern "C" void kernel_launch(void* const* d_in, const int* in_sizes, int n_in,
                              void* d_out, int out_size, void* d_ws, size_t ws_size,
                              hipStream_t stream) {
  const float* x      = (const float*)d_in[0];
  const float* sims   = (const float*)d_in[1];
  const float* w_qk   = (const float*)d_in[2];
  const float* w_v    = (const float*)d_in[3];
  const float* w_proj = (const float*)d_in[4];
  const float* b_proj = (const float*)d_in[5];
  float* outp  = (float*)d_out;
  float* qkv   = (float*)d_ws;                    // 18432*256*4 = 18.9 MB
  float* w_qs  = qkv + (size_t)18432 * 256;       // 4096 floats
  float* w_vp0 = w_qs + 4096;                     // 4096 floats
  float* w_vp1 = w_vp0 + 4096;                    // 4096 floats

  prep_kernel<<<dim3(1), dim3(256), 0, stream>>>(w_qk, w_v, w_proj, w_qs,
                                                 w_vp0, w_vp1);
  qkv_proj_kernel<<<dim3(1152), dim3(256), 0, stream>>>(x, w_qk, w_qs, w_vp0,
                                                        w_vp1, qkv);
  attn_fused_kernel<<<dim3(2304), dim3(512), 0, stream>>>(qkv, sims, b_proj,
                                                          outp);
}